// Round 5
// baseline (451.334 us; speedup 1.0000x reference)
//
#include <hip/hip_runtime.h>
#include <hip/hip_fp16.h>

// DenseMLP fused f16-MFMA implementation for gfx950.
// Math: out0 = silu(x@W0^T+b0)
//       for i=1..7: s = silu(sum_{j<i} out_j @ C[j,i]^T + bh[i-1]),
//                   C[j,i] = Wh[i-1] @ Wp[j*7+(i-1)]
//                   out_i = s @ (I+F[i,i])^T + sum_{k<i} out_k @ F[i,k]^T   (i<7)
//                   F[i,k] = sum_{j=i+1..7} Wf[k*7+(j-1)]
//       out_7 = s_7;  logits = out_7 @ Wout^T + bout; log_softmax.
//
// layersB: 64 rows/wave (4 row-tiles) so each B-frag load feeds 4 MFMAs:
// weight L1/L2 traffic = 1024 waves * 450KB = 460MB (vs 1.8GB at 16 rows/wave).
// VGPR state: stA[8][4][2] half8 = 256 regs -> launch_bounds(256,1).
// silu uses v_rcp_f32 (__builtin_amdgcn_rcpf) instead of the full-precision
// v_div_* sequence: ~13 cycles saved per silu wave-op on the serial chain.

typedef _Float16 half8 __attribute__((ext_vector_type(8)));
typedef float    f32x4 __attribute__((ext_vector_type(4)));

// ---- ws byte layout ----
constexpr int MAT_OFF  = 0;                      // 55 mats * 8KB = 450560
constexpr int W0F_OFF  = 55 * 8192;              // 25*4096 = 102400
constexpr int WOUT_OFF = W0F_OFF + 25 * 4096;    // 2048 (reserve 4096)
constexpr int S0_OFF   = WOUT_OFF + 4096;        // 4096 rowtiles * 2KB = 8MB

__host__ __device__ constexpr int cIdx(int i, int j) { return (i - 1) * i / 2 + j; } // i in 1..7
__host__ __device__ constexpr int fOff(int i) {       // i in 1..6
    return (i == 1) ? 0 : (i == 2) ? 2 : (i == 3) ? 5 : (i == 4) ? 9 : (i == 5) ? 14 : 20;
}
__host__ __device__ constexpr int fIdx(int i, int k) { return 28 + fOff(i) + k; }

__device__ __forceinline__ float fast_silu(float v) {
    // v * 1/(1+e^-v); v_rcp_f32 is <=1 ulp, negligible vs f16 matmul rounding.
    return v * __builtin_amdgcn_rcpf(1.f + __expf(-v));
}

// D-frag (4 col-tiles x f32x4) -> A-frag (2 x half8) via per-wave LDS scratch.
// Unswizzled address: hw = (c>>1)*512 + X*8 + (m&7), X = ((2(c&1)+(m>>3))<<4) + 4g + j.
// X == destination A-frag lane index; read hw = h*512 + lane*8 + e. Bijective.
// Bank swizzle: X ^= X>>3 applied on BOTH write and read (same hw transform) ->
// write banks spread from 4-way conflict to ~2-way (free); reads remain 16B blocks.
__device__ __forceinline__ void dToA(_Float16* sw, int lane, const f32x4* v, half8* out) {
    const int m = lane & 15, g = lane >> 4;
#pragma unroll
    for (int c = 0; c < 4; ++c) {
        const int kh = c >> 1;
        const int lp = (2 * (c & 1) + (m >> 3)) << 4;
#pragma unroll
        for (int j = 0; j < 4; ++j) {
            const int X = lp + 4 * g + j;
            sw[kh * 512 + ((X ^ (X >> 3)) << 3) + (m & 7)] = (_Float16)v[c][j];
        }
    }
    const int ls = (lane ^ (lane >> 3)) << 3;
    // same-wave DS ops; compiler orders via lgkmcnt (aliasing on sw).
    out[0] = *(const half8*)(sw + ls);
    out[1] = *(const half8*)(sw + 512 + ls);
}

// ---------------- Prep 1: C and F matrices -> f16 B-frag order ----------------
__global__ void prep_mats(const float* __restrict__ Wh, const float* __restrict__ Wp,
                          const float* __restrict__ Wf, char* __restrict__ wsb) {
    __shared__ float M[64][64];
    const int b = blockIdx.x, tid = threadIdx.x;
    const int m = tid >> 2, q = tid & 3;   // thread computes M[m][q*16 .. q*16+15]
    float acc[16];
#pragma unroll
    for (int u = 0; u < 16; ++u) acc[u] = 0.f;

    if (b < 28) {
        // C[j,i] = Wh[i-1] @ Wp[j*7+(i-1)]
        int i = 1;
        while (i < 7 && i * (i + 1) / 2 <= b) ++i;
        const int j = b - (i - 1) * i / 2;
        const float* wh = Wh + (size_t)(i - 1) * 4096;
        const float* wp = Wp + (size_t)(j * 7 + (i - 1)) * 4096;
        for (int t = 0; t < 64; ++t) {
            const float a = wh[m * 64 + t];
            const float* r = wp + t * 64 + q * 16;
#pragma unroll
            for (int u = 0; u < 16; ++u) acc[u] += a * r[u];
        }
    } else {
        // F[i,k] = sum_{jj=i+1..7} Wf[k*7+(jj-1)]  (+I if k==i)
        const int rr = b - 28;
        int i = 1;
        while (i < 6 && fOff(i + 1) <= rr) ++i;
        const int k = rr - fOff(i);
        for (int jj = i + 1; jj <= 7; ++jj) {
            const float* wf = Wf + (size_t)(k * 7 + (jj - 1)) * 4096 + m * 64 + q * 16;
#pragma unroll
            for (int u = 0; u < 16; ++u) acc[u] += wf[u];
        }
        if (k == i) {
#pragma unroll
            for (int u = 0; u < 16; ++u) acc[u] += (m == q * 16 + u) ? 1.0f : 0.0f;
        }
    }
#pragma unroll
    for (int u = 0; u < 16; ++u) M[m][q * 16 + u] = acc[u];
    __syncthreads();

    // B-frag write: chunk qq=c*2+h: lane l holds M[c*16+(l&15)][h*32+(l>>4)*8+e]
    const int lane = tid & 63;
#pragma unroll
    for (int rep = 0; rep < 2; ++rep) {
        const int qq = (tid >> 6) + rep * 4;
        const int c = qq >> 1, h = qq & 1;
        const int rowM = c * 16 + (lane & 15);
        const int kb = h * 32 + (lane >> 4) * 8;
        half8 o;
#pragma unroll
        for (int e = 0; e < 8; ++e) o[e] = (_Float16)M[rowM][kb + e];
        *(half8*)(wsb + MAT_OFF + (size_t)b * 8192 + qq * 1024 + lane * 16) = o;
    }
}

// ---------------- Prep 2: W0 (zero-padded K=800) and Wout -> f16 frag order ----------------
__global__ void prep_w0(const float* __restrict__ W0, const float* __restrict__ Wout,
                        char* __restrict__ wsb) {
    const int b = blockIdx.x, tid = threadIdx.x;
    const int lane = tid & 63;
    if (b < 25) {
        const int c = tid >> 6;
        const int rowW = c * 16 + (lane & 15);
        const int kb = b * 32 + (lane >> 4) * 8;
        half8 o;
#pragma unroll
        for (int e = 0; e < 8; ++e) {
            const int k = kb + e;
            o[e] = (k < 784) ? (_Float16)W0[(size_t)rowW * 784 + k] : (_Float16)0.f;
        }
        *(half8*)(wsb + W0F_OFF + (size_t)(b * 4 + c) * 1024 + lane * 16) = o;
    } else {
        if (tid < 128) {
            const int h = tid >> 6;
            const int mcol = lane & 15;
            const int kb = h * 32 + (lane >> 4) * 8;
            half8 o;
#pragma unroll
            for (int e = 0; e < 8; ++e)
                o[e] = (mcol < 10) ? (_Float16)Wout[mcol * 64 + kb + e] : (_Float16)0.f;
            *(half8*)(wsb + WOUT_OFF + (size_t)(h * 64 + lane) * 16) = o;
        }
    }
}

// ---------------- Kernel A: layer 0 (streaming 65536x784 @ 784x64 + silu) ----------------
__global__ __launch_bounds__(256, 4) void layer0(const float* __restrict__ x,
                                                 const float* __restrict__ b0,
                                                 char* __restrict__ wsb) {
    __shared__ __align__(16) _Float16 scr0[4][1024];   // 2KB per wave
    const int tid = threadIdx.x, lane = tid & 63, wv = tid >> 6;
    const int rt = blockIdx.x * 4 + wv;
    const int m = lane & 15, g = lane >> 4;
    const float* xrow = x + (size_t)(rt * 16 + m) * 784;
    const int ko = g * 8;
    const half8* w0f = (const half8*)(wsb + W0F_OFF);

    f32x4 acc[4];
#pragma unroll
    for (int c = 0; c < 4; ++c) acc[c] = (f32x4){0.f, 0.f, 0.f, 0.f};

#pragma unroll
    for (int t = 0; t < 24; ++t) {
        const f32x4 u0 = *(const f32x4*)(xrow + t * 32 + ko);
        const f32x4 u1 = *(const f32x4*)(xrow + t * 32 + ko + 4);
        half8 a;
#pragma unroll
        for (int e = 0; e < 4; ++e) { a[e] = (_Float16)u0[e]; a[4 + e] = (_Float16)u1[e]; }
#pragma unroll
        for (int c = 0; c < 4; ++c)
            acc[c] = __builtin_amdgcn_mfma_f32_16x16x32_f16(a, w0f[(t * 4 + c) * 64 + lane],
                                                            acc[c], 0, 0, 0);
    }
    {   // t = 24 peel: k = 768 + ko, valid only for ko < 16 (row len 784)
        half8 a;
#pragma unroll
        for (int e = 0; e < 8; ++e) a[e] = (_Float16)0.f;
        if (ko < 16) {
            const f32x4 u0 = *(const f32x4*)(xrow + 768 + ko);
            const f32x4 u1 = *(const f32x4*)(xrow + 768 + ko + 4);
#pragma unroll
            for (int e = 0; e < 4; ++e) { a[e] = (_Float16)u0[e]; a[4 + e] = (_Float16)u1[e]; }
        }
#pragma unroll
        for (int c = 0; c < 4; ++c)
            acc[c] = __builtin_amdgcn_mfma_f32_16x16x32_f16(a, w0f[(24 * 4 + c) * 64 + lane],
                                                            acc[c], 0, 0, 0);
    }
    // bias + silu in D-frag, then LDS D->A, then coalesced 16B stores
#pragma unroll
    for (int c = 0; c < 4; ++c) {
        const float bb = b0[c * 16 + m];
#pragma unroll
        for (int j = 0; j < 4; ++j)
            acc[c][j] = fast_silu(acc[c][j] + bb);
    }
    half8 sA[2];
    dToA(&scr0[wv][0], lane, acc, sA);
    char* s0 = wsb + S0_OFF + (size_t)rt * 2048;
    *(half8*)(s0 + lane * 16) = sA[0];
    *(half8*)(s0 + 1024 + lane * 16) = sA[1];
}

// ---------------- Kernel B: layers 1..7 + head + log_softmax ----------------
// 64 rows per wave (4 row-tiles): each B-frag load serves 4 MFMAs.
__global__ __launch_bounds__(256, 1) void layersB(const float* __restrict__ bh,
                                                  const float* __restrict__ bout,
                                                  const char* __restrict__ wsb,
                                                  float* __restrict__ dOut) {
    __shared__ __align__(16) _Float16 scrh[4][1024];   // 2KB per wave
    const int tid = threadIdx.x, lane = tid & 63, wv = tid >> 6;
    const int rg = blockIdx.x * 4 + wv;                // 64-row group, 0..1023
    const int m = lane & 15, g = lane >> 4;
    _Float16* sw = &scrh[wv][0];
    const half8* wm = (const half8*)(wsb + MAT_OFF);

    half8 stA[8][4][2];   // [layer][row-tile][k-half] A-frags in VGPRs (256 VGPRs)
#pragma unroll
    for (int t = 0; t < 4; ++t) {
        const char* s0 = wsb + S0_OFF + ((size_t)(rg * 4 + t)) * 2048;
        stA[0][t][0] = *(const half8*)(s0 + lane * 16);
        stA[0][t][1] = *(const half8*)(s0 + 1024 + lane * 16);
    }

    f32x4 accL[4];
#pragma unroll
    for (int t = 0; t < 4; ++t) accL[t] = (f32x4){0.f, 0.f, 0.f, 0.f};

#pragma unroll
    for (int i = 1; i < 8; ++i) {
        f32x4 acc[4][4];   // [row-tile][col-tile]
#pragma unroll
        for (int c = 0; c < 4; ++c) {
            const float bb = bh[(i - 1) * 64 + c * 16 + m];
#pragma unroll
            for (int t = 0; t < 4; ++t) acc[t][c] = (f32x4){bb, bb, bb, bb};
        }
#pragma unroll
        for (int j = 0; j < i; ++j) {
            const int slot = cIdx(i, j);
#pragma unroll
            for (int c = 0; c < 4; ++c)
#pragma unroll
                for (int h = 0; h < 2; ++h) {
                    const half8 bf = wm[slot * 512 + (c * 2 + h) * 64 + lane];
#pragma unroll
                    for (int t = 0; t < 4; ++t)
                        acc[t][c] = __builtin_amdgcn_mfma_f32_16x16x32_f16(stA[j][t][h], bf,
                                                                           acc[t][c], 0, 0, 0);
                }
        }
        // silu
#pragma unroll
        for (int t = 0; t < 4; ++t)
#pragma unroll
            for (int c = 0; c < 4; ++c)
#pragma unroll
                for (int j = 0; j < 4; ++j)
                    acc[t][c][j] = fast_silu(acc[t][c][j]);
        half8 sA[4][2];
#pragma unroll
        for (int t = 0; t < 4; ++t) dToA(sw, lane, acc[t], sA[t]);

        if (i < 7) {
            f32x4 accO[4][4];
#pragma unroll
            for (int t = 0; t < 4; ++t)
#pragma unroll
                for (int c = 0; c < 4; ++c) accO[t][c] = (f32x4){0.f, 0.f, 0.f, 0.f};
#pragma unroll
            for (int k = 0; k < i; ++k) {
                const int slot = fIdx(i, k);
#pragma unroll
                for (int c = 0; c < 4; ++c)
#pragma unroll
                    for (int h = 0; h < 2; ++h) {
                        const half8 bf = wm[slot * 512 + (c * 2 + h) * 64 + lane];
#pragma unroll
                        for (int t = 0; t < 4; ++t)
                            accO[t][c] = __builtin_amdgcn_mfma_f32_16x16x32_f16(
                                stA[k][t][h], bf, accO[t][c], 0, 0, 0);
                    }
            }
            {   // self term with (I + F[i,i])
                const int slot = fIdx(i, i);
#pragma unroll
                for (int c = 0; c < 4; ++c)
#pragma unroll
                    for (int h = 0; h < 2; ++h) {
                        const half8 bf = wm[slot * 512 + (c * 2 + h) * 64 + lane];
#pragma unroll
                        for (int t = 0; t < 4; ++t)
                            accO[t][c] = __builtin_amdgcn_mfma_f32_16x16x32_f16(
                                sA[t][h], bf, accO[t][c], 0, 0, 0);
                    }
            }
#pragma unroll
            for (int t = 0; t < 4; ++t) dToA(sw, lane, accO[t], &stA[i][t][0]);
        } else {
            // logits = s7 @ Wout^T  (single 16-col tile, K=64), per row-tile
            const half8* wo = (const half8*)(wsb + WOUT_OFF);
            const half8 wo0 = wo[lane], wo1 = wo[64 + lane];
#pragma unroll
            for (int t = 0; t < 4; ++t) {
                accL[t] = __builtin_amdgcn_mfma_f32_16x16x32_f16(sA[t][0], wo0, accL[t], 0, 0, 0);
                accL[t] = __builtin_amdgcn_mfma_f32_16x16x32_f16(sA[t][1], wo1, accL[t], 0, 0, 0);
            }
        }
    }

    // + bout, log_softmax over cols 0..9, store (per row-tile)
    const float bb = (m < 10) ? bout[m] : 0.f;
#pragma unroll
    for (int t = 0; t < 4; ++t)
#pragma unroll
        for (int j = 0; j < 4; ++j) {
            const float logit = accL[t][j] + bb;
            float mx = (m < 10) ? logit : -1e30f;
#pragma unroll
            for (int d = 1; d < 16; d <<= 1) mx = fmaxf(mx, __shfl_xor(mx, d, 16));
            const float e = (m < 10) ? __expf(logit - mx) : 0.f;
            float sum = e;
#pragma unroll
            for (int d = 1; d < 16; d <<= 1) sum += __shfl_xor(sum, d, 16);
            const float ls = logit - mx - __logf(sum);
            if (m < 10) dOut[(size_t)(rg * 64 + t * 16 + 4 * g + j) * 10 + m] = ls;
        }
}

extern "C" void kernel_launch(void* const* d_in, const int* in_sizes, int n_in,
                              void* d_out, int out_size, void* d_ws, size_t ws_size,
                              hipStream_t stream) {
    (void)in_sizes; (void)n_in; (void)out_size; (void)ws_size;
    const float* x    = (const float*)d_in[0];
    const float* W0   = (const float*)d_in[1];
    const float* b0   = (const float*)d_in[2];
    const float* Wh   = (const float*)d_in[3];
    const float* bh   = (const float*)d_in[4];
    const float* Wp   = (const float*)d_in[5];
    const float* Wf   = (const float*)d_in[6];
    const float* Wout = (const float*)d_in[7];
    const float* bout = (const float*)d_in[8];
    char* wsb = (char*)d_ws;
    float* out = (float*)d_out;

    hipLaunchKernelGGL(prep_mats, dim3(55), dim3(256), 0, stream, Wh, Wp, Wf, wsb);
    hipLaunchKernelGGL(prep_w0,   dim3(26), dim3(256), 0, stream, W0, Wout, wsb);
    hipLaunchKernelGGL(layer0,    dim3(1024), dim3(256), 0, stream, x, b0, wsb);
    hipLaunchKernelGGL(layersB,   dim3(256),  dim3(256), 0, stream, bh, bout, wsb, out);
}

// Round 6
// 389.895 us; speedup vs baseline: 1.1576x; 1.1576x over previous
//
#include <hip/hip_runtime.h>
#include <hip/hip_fp16.h>

// DenseMLP fused f16-MFMA implementation for gfx950.
// Math: out0 = silu(x@W0^T+b0)
//       for i=1..7: s = silu(sum_{j<i} out_j @ C[j,i]^T + bh[i-1]),
//                   C[j,i] = Wh[i-1] @ Wp[j*7+(i-1)]
//                   out_i = s @ (I+F[i,i])^T + sum_{k<i} out_k @ F[i,k]^T   (i<7)
//                   F[i,k] = sum_{j=i+1..7} Wf[k*7+(j-1)]
//       out_7 = s_7;  logits = out_7 @ Wout^T + bout; log_softmax.
//
// R5 lesson (measured): 64-row/wave layersB spilled (VGPR_Count=200 < state
// size) -> 128us latency-bound, MfmaUtil 9%. This version: 32 rows/wave
// (state 128 regs, peak ~250 <= 256 @ 2 waves/SIMD) + explicit double-buffered
// B-frag prefetch so every weight load is issued one term (16 MFMAs) ahead.

typedef _Float16 half8 __attribute__((ext_vector_type(8)));
typedef float    f32x4 __attribute__((ext_vector_type(4)));

// ---- ws byte layout ----
constexpr int MAT_OFF  = 0;                      // 55 mats * 8KB = 450560
constexpr int W0F_OFF  = 55 * 8192;              // 25*4096 = 102400
constexpr int WOUT_OFF = W0F_OFF + 25 * 4096;    // 2048 (reserve 4096)
constexpr int S0_OFF   = WOUT_OFF + 4096;        // 4096 rowtiles * 2KB = 8MB

__host__ __device__ constexpr int cIdx(int i, int j) { return (i - 1) * i / 2 + j; } // i in 1..7
__host__ __device__ constexpr int fOff(int i) {       // i in 1..6
    return (i == 1) ? 0 : (i == 2) ? 2 : (i == 3) ? 5 : (i == 4) ? 9 : (i == 5) ? 14 : 20;
}
__host__ __device__ constexpr int fIdx(int i, int k) { return 28 + fOff(i) + k; }

__device__ __forceinline__ float fast_silu(float v) {
    return v * __builtin_amdgcn_rcpf(1.f + __expf(-v));
}

// Load one 64x64 term's 8 B-frags (16B/lane each) into a register buffer.
__device__ __forceinline__ void loadTerm(half8 (&buf)[8], const half8* __restrict__ wm,
                                         int slot, int lane) {
#pragma unroll
    for (int q = 0; q < 8; ++q) buf[q] = wm[slot * 512 + q * 64 + lane];
}

// 16 MFMAs of one term applied to two row-tiles (B-frag reused 2x).
__device__ __forceinline__ void term16(const half8 (&bfs)[8], const half8 (&a0)[2],
                                       const half8 (&a1)[2], f32x4 (&c0)[4], f32x4 (&c1)[4]) {
#pragma unroll
    for (int c = 0; c < 4; ++c)
#pragma unroll
        for (int h = 0; h < 2; ++h) {
            const half8 bf = bfs[c * 2 + h];
            c0[c] = __builtin_amdgcn_mfma_f32_16x16x32_f16(a0[h], bf, c0[c], 0, 0, 0);
            c1[c] = __builtin_amdgcn_mfma_f32_16x16x32_f16(a1[h], bf, c1[c], 0, 0, 0);
        }
}

// D-frag (4 col-tiles x f32x4) -> A-frag (2 x half8) via per-wave LDS scratch.
// hw = (c>>1)*512 + X*8 + (m&7), X = ((2(c&1)+(m>>3))<<4) + 4g + j; X == dest
// A-frag lane; read hw = h*512 + lane*8 + e. Bijective. Bank swizzle X^=X>>3
// on BOTH sides (write-conflict 4-way -> ~2-way; reads stay 16B blocks).
__device__ __forceinline__ void dToA(_Float16* sw, int lane, const f32x4* v, half8* out) {
    const int m = lane & 15, g = lane >> 4;
#pragma unroll
    for (int c = 0; c < 4; ++c) {
        const int kh = c >> 1;
        const int lp = (2 * (c & 1) + (m >> 3)) << 4;
#pragma unroll
        for (int j = 0; j < 4; ++j) {
            const int X = lp + 4 * g + j;
            sw[kh * 512 + ((X ^ (X >> 3)) << 3) + (m & 7)] = (_Float16)v[c][j];
        }
    }
    const int ls = (lane ^ (lane >> 3)) << 3;
    out[0] = *(const half8*)(sw + ls);
    out[1] = *(const half8*)(sw + 512 + ls);
}

// ---------------- Prep 1: C and F matrices -> f16 B-frag order ----------------
__global__ void prep_mats(const float* __restrict__ Wh, const float* __restrict__ Wp,
                          const float* __restrict__ Wf, char* __restrict__ wsb) {
    __shared__ float M[64][64];
    const int b = blockIdx.x, tid = threadIdx.x;
    const int m = tid >> 2, q = tid & 3;   // thread computes M[m][q*16 .. q*16+15]
    float acc[16];
#pragma unroll
    for (int u = 0; u < 16; ++u) acc[u] = 0.f;

    if (b < 28) {
        // C[j,i] = Wh[i-1] @ Wp[j*7+(i-1)]
        int i = 1;
        while (i < 7 && i * (i + 1) / 2 <= b) ++i;
        const int j = b - (i - 1) * i / 2;
        const float* wh = Wh + (size_t)(i - 1) * 4096;
        const float* wp = Wp + (size_t)(j * 7 + (i - 1)) * 4096;
#pragma unroll 4
        for (int t = 0; t < 64; ++t) {
            const float a = wh[m * 64 + t];
            const f32x4* r = (const f32x4*)(wp + t * 64 + q * 16);
            const f32x4 r0 = r[0], r1 = r[1], r2 = r[2], r3 = r[3];
#pragma unroll
            for (int u = 0; u < 4; ++u) {
                acc[u]      += a * r0[u];
                acc[4 + u]  += a * r1[u];
                acc[8 + u]  += a * r2[u];
                acc[12 + u] += a * r3[u];
            }
        }
    } else {
        // F[i,k] = sum_{jj=i+1..7} Wf[k*7+(jj-1)]  (+I if k==i)
        const int rr = b - 28;
        int i = 1;
        while (i < 6 && fOff(i + 1) <= rr) ++i;
        const int k = rr - fOff(i);
        for (int jj = i + 1; jj <= 7; ++jj) {
            const f32x4* wf = (const f32x4*)(Wf + (size_t)(k * 7 + (jj - 1)) * 4096 + m * 64 + q * 16);
            const f32x4 r0 = wf[0], r1 = wf[1], r2 = wf[2], r3 = wf[3];
#pragma unroll
            for (int u = 0; u < 4; ++u) {
                acc[u]      += r0[u];
                acc[4 + u]  += r1[u];
                acc[8 + u]  += r2[u];
                acc[12 + u] += r3[u];
            }
        }
        if (k == i) {
#pragma unroll
            for (int u = 0; u < 16; ++u) acc[u] += (m == q * 16 + u) ? 1.0f : 0.0f;
        }
    }
#pragma unroll
    for (int u = 0; u < 16; ++u) M[m][q * 16 + u] = acc[u];
    __syncthreads();

    // B-frag write: chunk qq=c*2+h: lane l holds M[c*16+(l&15)][h*32+(l>>4)*8+e]
    const int lane = tid & 63;
#pragma unroll
    for (int rep = 0; rep < 2; ++rep) {
        const int qq = (tid >> 6) + rep * 4;
        const int c = qq >> 1, h = qq & 1;
        const int rowM = c * 16 + (lane & 15);
        const int kb = h * 32 + (lane >> 4) * 8;
        half8 o;
#pragma unroll
        for (int e = 0; e < 8; ++e) o[e] = (_Float16)M[rowM][kb + e];
        *(half8*)(wsb + MAT_OFF + (size_t)b * 8192 + qq * 1024 + lane * 16) = o;
    }
}

// ---------------- Prep 2: W0 (zero-padded K=800) and Wout -> f16 frag order ----------------
__global__ void prep_w0(const float* __restrict__ W0, const float* __restrict__ Wout,
                        char* __restrict__ wsb) {
    const int b = blockIdx.x, tid = threadIdx.x;
    const int lane = tid & 63;
    if (b < 25) {
        const int c = tid >> 6;
        const int rowW = c * 16 + (lane & 15);
        const int kb = b * 32 + (lane >> 4) * 8;
        half8 o;
#pragma unroll
        for (int e = 0; e < 8; ++e) {
            const int k = kb + e;
            o[e] = (k < 784) ? (_Float16)W0[(size_t)rowW * 784 + k] : (_Float16)0.f;
        }
        *(half8*)(wsb + W0F_OFF + (size_t)(b * 4 + c) * 1024 + lane * 16) = o;
    } else {
        if (tid < 128) {
            const int h = tid >> 6;
            const int mcol = lane & 15;
            const int kb = h * 32 + (lane >> 4) * 8;
            half8 o;
#pragma unroll
            for (int e = 0; e < 8; ++e)
                o[e] = (mcol < 10) ? (_Float16)Wout[mcol * 64 + kb + e] : (_Float16)0.f;
            *(half8*)(wsb + WOUT_OFF + (size_t)(h * 64 + lane) * 16) = o;
        }
    }
}

// ---------------- Kernel A: layer 0 (streaming 65536x784 @ 784x64 + silu) ----------------
__global__ __launch_bounds__(256, 4) void layer0(const float* __restrict__ x,
                                                 const float* __restrict__ b0,
                                                 char* __restrict__ wsb) {
    __shared__ __align__(16) _Float16 scr0[4][1024];   // 2KB per wave
    const int tid = threadIdx.x, lane = tid & 63, wv = tid >> 6;
    const int rt = blockIdx.x * 4 + wv;
    const int m = lane & 15, g = lane >> 4;
    const float* xrow = x + (size_t)(rt * 16 + m) * 784;
    const int ko = g * 8;
    const half8* w0f = (const half8*)(wsb + W0F_OFF);

    f32x4 acc[4];
#pragma unroll
    for (int c = 0; c < 4; ++c) acc[c] = (f32x4){0.f, 0.f, 0.f, 0.f};

#pragma unroll
    for (int t = 0; t < 24; ++t) {
        const f32x4 u0 = *(const f32x4*)(xrow + t * 32 + ko);
        const f32x4 u1 = *(const f32x4*)(xrow + t * 32 + ko + 4);
        half8 a;
#pragma unroll
        for (int e = 0; e < 4; ++e) { a[e] = (_Float16)u0[e]; a[4 + e] = (_Float16)u1[e]; }
#pragma unroll
        for (int c = 0; c < 4; ++c)
            acc[c] = __builtin_amdgcn_mfma_f32_16x16x32_f16(a, w0f[(t * 4 + c) * 64 + lane],
                                                            acc[c], 0, 0, 0);
    }
    {   // t = 24 peel: k = 768 + ko, valid only for ko < 16 (row len 784)
        half8 a;
#pragma unroll
        for (int e = 0; e < 8; ++e) a[e] = (_Float16)0.f;
        if (ko < 16) {
            const f32x4 u0 = *(const f32x4*)(xrow + 768 + ko);
            const f32x4 u1 = *(const f32x4*)(xrow + 768 + ko + 4);
#pragma unroll
            for (int e = 0; e < 4; ++e) { a[e] = (_Float16)u0[e]; a[4 + e] = (_Float16)u1[e]; }
        }
#pragma unroll
        for (int c = 0; c < 4; ++c)
            acc[c] = __builtin_amdgcn_mfma_f32_16x16x32_f16(a, w0f[(24 * 4 + c) * 64 + lane],
                                                            acc[c], 0, 0, 0);
    }
#pragma unroll
    for (int c = 0; c < 4; ++c) {
        const float bb = b0[c * 16 + m];
#pragma unroll
        for (int j = 0; j < 4; ++j)
            acc[c][j] = fast_silu(acc[c][j] + bb);
    }
    half8 sA[2];
    dToA(&scr0[wv][0], lane, acc, sA);
    char* s0 = wsb + S0_OFF + (size_t)rt * 2048;
    *(half8*)(s0 + lane * 16) = sA[0];
    *(half8*)(s0 + 1024 + lane * 16) = sA[1];
}

// ---------------- Kernel B: layers 1..7 + head + log_softmax ----------------
// 32 rows/wave; explicit double-buffered B-frag prefetch (pf0/pf1), parity
// tracked at compile time: term counter at start of layer i is i*i-1.
__global__ __launch_bounds__(256, 2) void layersB(const float* __restrict__ bh,
                                                  const float* __restrict__ bout,
                                                  const char* __restrict__ wsb,
                                                  float* __restrict__ dOut) {
    __shared__ __align__(16) _Float16 scrh[4][2][1024];   // 2 x 2KB per wave
    const int tid = threadIdx.x, lane = tid & 63, wv = tid >> 6;
    const int rt2 = blockIdx.x * 4 + wv;               // 32-row group, 0..2047
    const int m = lane & 15, g = lane >> 4;
    _Float16* sw0 = &scrh[wv][0][0];
    _Float16* sw1 = &scrh[wv][1][0];
    const half8* wm = (const half8*)(wsb + MAT_OFF);

    half8 stA[8][2][2];   // [layer][row-tile][k-half] (128 VGPRs)
#pragma unroll
    for (int t = 0; t < 2; ++t) {
        const char* s0 = wsb + S0_OFF + (size_t)(rt2 * 2 + t) * 2048;
        stA[0][t][0] = *(const half8*)(s0 + lane * 16);
        stA[0][t][1] = *(const half8*)(s0 + 1024 + lane * 16);
    }

    half8 pf0[8], pf1[8];
    loadTerm(pf0, wm, cIdx(1, 0), lane);   // term 0 prefetch

    f32x4 accL[2];
    accL[0] = (f32x4){0.f, 0.f, 0.f, 0.f};
    accL[1] = (f32x4){0.f, 0.f, 0.f, 0.f};

#pragma unroll
    for (int i = 1; i < 8; ++i) {
        const int nb = i * i - 1;   // global term counter at layer start
        f32x4 acc[2][4];
#pragma unroll
        for (int c = 0; c < 4; ++c) {
            const float bb = bh[(i - 1) * 64 + c * 16 + m];
            acc[0][c] = (f32x4){bb, bb, bb, bb};
            acc[1][c] = (f32x4){bb, bb, bb, bb};
        }
        // ---- C-phase: sum_j out_j @ C[j,i]^T ----
#pragma unroll
        for (int tc = 0; tc < i; ++tc) {
            const bool hn = (tc + 1 < i) || (i < 7);
            const int ns = (tc + 1 < i) ? cIdx(i, tc + 1) : (i < 7 ? fIdx(i, 0) : 0);
            if (((nb + tc) & 1) == 0) {
                if (hn) loadTerm(pf1, wm, ns, lane);
                term16(pf0, stA[tc][0], stA[tc][1], acc[0], acc[1]);
            } else {
                if (hn) loadTerm(pf0, wm, ns, lane);
                term16(pf1, stA[tc][0], stA[tc][1], acc[0], acc[1]);
            }
        }
        // silu + D->A (F-term-0 loads are already in flight, hidden here)
#pragma unroll
        for (int t = 0; t < 2; ++t)
#pragma unroll
            for (int c = 0; c < 4; ++c)
#pragma unroll
                for (int j = 0; j < 4; ++j)
                    acc[t][c][j] = fast_silu(acc[t][c][j]);
        half8 sA[2][2];
        dToA(sw0, lane, acc[0], sA[0]);
        dToA(sw1, lane, acc[1], sA[1]);

        if (i < 7) {
            f32x4 accO[2][4];
#pragma unroll
            for (int t = 0; t < 2; ++t)
#pragma unroll
                for (int c = 0; c < 4; ++c) accO[t][c] = (f32x4){0.f, 0.f, 0.f, 0.f};
            // ---- F-phase: sum_{k<i} out_k @ F[i,k]^T ----
#pragma unroll
            for (int k = 0; k < i; ++k) {
                const int ns = (k + 1 < i) ? fIdx(i, k + 1) : fIdx(i, i);
                if (((nb + i + k) & 1) == 0) {
                    loadTerm(pf1, wm, ns, lane);
                    term16(pf0, stA[k][0], stA[k][1], accO[0], accO[1]);
                } else {
                    loadTerm(pf0, wm, ns, lane);
                    term16(pf1, stA[k][0], stA[k][1], accO[0], accO[1]);
                }
            }
            {   // self term (I + F[i,i]); prefetch next layer's first C term
                const int ns = cIdx(i + 1, 0);
                if (((nb + 2 * i) & 1) == 0) {
                    loadTerm(pf1, wm, ns, lane);
                    term16(pf0, sA[0], sA[1], accO[0], accO[1]);
                } else {
                    loadTerm(pf0, wm, ns, lane);
                    term16(pf1, sA[0], sA[1], accO[0], accO[1]);
                }
            }
            dToA(sw0, lane, accO[0], &stA[i][0][0]);
            dToA(sw1, lane, accO[1], &stA[i][1][0]);
        } else {
            // logits = s7 @ Wout^T (single 16-col tile, K=64), per row-tile
            const half8* wo = (const half8*)(wsb + WOUT_OFF);
            const half8 wo0 = wo[lane], wo1 = wo[64 + lane];
#pragma unroll
            for (int t = 0; t < 2; ++t) {
                accL[t] = __builtin_amdgcn_mfma_f32_16x16x32_f16(sA[t][0], wo0, accL[t], 0, 0, 0);
                accL[t] = __builtin_amdgcn_mfma_f32_16x16x32_f16(sA[t][1], wo1, accL[t], 0, 0, 0);
            }
        }
    }

    // + bout, log_softmax over cols 0..9, store (per row-tile)
    const float bb = (m < 10) ? bout[m] : 0.f;
#pragma unroll
    for (int t = 0; t < 2; ++t)
#pragma unroll
        for (int j = 0; j < 4; ++j) {
            const float logit = accL[t][j] + bb;
            float mx = (m < 10) ? logit : -1e30f;
#pragma unroll
            for (int d = 1; d < 16; d <<= 1) mx = fmaxf(mx, __shfl_xor(mx, d, 16));
            const float e = (m < 10) ? __expf(logit - mx) : 0.f;
            float sum = e;
#pragma unroll
            for (int d = 1; d < 16; d <<= 1) sum += __shfl_xor(sum, d, 16);
            const float ls = logit - mx - __logf(sum);
            if (m < 10) dOut[(size_t)(rt2 * 32 + t * 16 + 4 * g + j) * 10 + m] = ls;
        }
}

extern "C" void kernel_launch(void* const* d_in, const int* in_sizes, int n_in,
                              void* d_out, int out_size, void* d_ws, size_t ws_size,
                              hipStream_t stream) {
    (void)in_sizes; (void)n_in; (void)out_size; (void)ws_size;
    const float* x    = (const float*)d_in[0];
    const float* W0   = (const float*)d_in[1];
    const float* b0   = (const float*)d_in[2];
    const float* Wh   = (const float*)d_in[3];
    const float* bh   = (const float*)d_in[4];
    const float* Wp   = (const float*)d_in[5];
    const float* Wf   = (const float*)d_in[6];
    const float* Wout = (const float*)d_in[7];
    const float* bout = (const float*)d_in[8];
    char* wsb = (char*)d_ws;
    float* out = (float*)d_out;

    hipLaunchKernelGGL(prep_mats, dim3(55), dim3(256), 0, stream, Wh, Wp, Wf, wsb);
    hipLaunchKernelGGL(prep_w0,   dim3(26), dim3(256), 0, stream, W0, Wout, wsb);
    hipLaunchKernelGGL(layer0,    dim3(1024), dim3(256), 0, stream, x, b0, wsb);
    hipLaunchKernelGGL(layersB,   dim3(512),  dim3(256), 0, stream, bh, bout, wsb, out);
}

// Round 8
// 360.085 us; speedup vs baseline: 1.2534x; 1.0828x over previous
//
#include <hip/hip_runtime.h>
#include <hip/hip_fp16.h>

// DenseMLP fused f16-MFMA implementation for gfx950.
// Math: out0 = silu(x@W0^T+b0)
//       for i=1..7: s = silu(sum_{j<i} out_j @ C[j,i]^T + bh[i-1]),
//                   C[j,i] = Wh[i-1] @ Wp[j*7+(i-1)]
//                   out_i = s @ (I+F[i,i])^T + sum_{k<i} out_k @ F[i,k]^T   (i<7)
//                   F[i,k] = sum_{j=i+1..7} Wf[k*7+(j-1)]
//       out_7 = s_7;  logits = out_7 @ Wout^T + bout; log_softmax.
//
// Two kernels total. prep_all (165 blocks) builds all frag-ordered weights;
// mlp_fused does layer0 (HBM streaming) + layers 1..7 + head per 32-row wave.
// F-phase does the self-term FIRST so sA dies early: peak live regs ~230 <
// 256 cap @ 2 waves/SIMD. Double-buffered B-frag prefetch; term parity:
// term T consumes pf[T&1]; per-layer order: C x i, self, F x i; nb = i*i-1.

typedef _Float16 half8 __attribute__((ext_vector_type(8)));
typedef float    f32x4 __attribute__((ext_vector_type(4)));

// ---- ws byte layout ----
constexpr int MAT_OFF  = 0;                      // 55 mats * 8KB = 450560
constexpr int W0F_OFF  = 55 * 8192;              // 25*4096 = 102400
constexpr int WOUT_OFF = W0F_OFF + 25 * 4096;    // 2048 (reserve 4096)

__host__ __device__ constexpr int cIdx(int i, int j) { return (i - 1) * i / 2 + j; } // i in 1..7
__host__ __device__ constexpr int fOff(int i) {       // i in 1..6
    return (i == 1) ? 0 : (i == 2) ? 2 : (i == 3) ? 5 : (i == 4) ? 9 : (i == 5) ? 14 : 20;
}
__host__ __device__ constexpr int fIdx(int i, int k) { return 28 + fOff(i) + k; }

__device__ __forceinline__ float fast_silu(float v) {
    return v * __builtin_amdgcn_rcpf(1.f + __expf(-v));
}

// Load one 64x64 term's 8 B-frags (16B/lane each) into a register buffer.
__device__ __forceinline__ void loadTerm(half8 (&buf)[8], const half8* __restrict__ wm,
                                         int slot, int lane) {
#pragma unroll
    for (int q = 0; q < 8; ++q) buf[q] = wm[slot * 512 + q * 64 + lane];
}

// 16 MFMAs of one term applied to two row-tiles (B-frag reused 2x).
__device__ __forceinline__ void term16(const half8 (&bfs)[8], const half8 (&a0)[2],
                                       const half8 (&a1)[2], f32x4 (&c0)[4], f32x4 (&c1)[4]) {
#pragma unroll
    for (int c = 0; c < 4; ++c)
#pragma unroll
        for (int h = 0; h < 2; ++h) {
            const half8 bf = bfs[c * 2 + h];
            c0[c] = __builtin_amdgcn_mfma_f32_16x16x32_f16(a0[h], bf, c0[c], 0, 0, 0);
            c1[c] = __builtin_amdgcn_mfma_f32_16x16x32_f16(a1[h], bf, c1[c], 0, 0, 0);
        }
}

// D-frag (4 col-tiles x f32x4) -> A-frag (2 x half8) via per-wave LDS scratch.
// hw = (c>>1)*512 + X*8 + (m&7), X = ((2(c&1)+(m>>3))<<4) + 4g + j; X == dest
// A-frag lane; read hw = h*512 + lane*8 + e. Bijective. Bank swizzle X^=X>>3
// on BOTH sides (write-conflict 4-way -> ~2-way; reads stay 16B blocks).
__device__ __forceinline__ void dToA(_Float16* sw, int lane, const f32x4* v, half8* out) {
    const int m = lane & 15, g = lane >> 4;
#pragma unroll
    for (int c = 0; c < 4; ++c) {
        const int kh = c >> 1;
        const int lp = (2 * (c & 1) + (m >> 3)) << 4;
#pragma unroll
        for (int j = 0; j < 4; ++j) {
            const int X = lp + 4 * g + j;
            sw[kh * 512 + ((X ^ (X >> 3)) << 3) + (m & 7)] = (_Float16)v[c][j];
        }
    }
    const int ls = (lane ^ (lane >> 3)) << 3;
    out[0] = *(const half8*)(sw + ls);
    out[1] = *(const half8*)(sw + 512 + ls);
}

// ---------------- prep_all: every weight -> f16 frag order, one launch ----------------
// blocks [0,112): C-matmuls, 4 blocks per matrix (16 rows each)
// blocks [112,139): F sums   blocks [139,164): W0   block 164: Wout
__global__ void prep_all(const float* __restrict__ W0, const float* __restrict__ Wout,
                         const float* __restrict__ Wh, const float* __restrict__ Wp,
                         const float* __restrict__ Wf, char* __restrict__ wsb) {
    __shared__ float M[64][64];
    const int b = blockIdx.x, tid = threadIdx.x;
    const int lane = tid & 63, wv = tid >> 6;

    if (b < 112) {
        // ---- C[j,i] = Wh[i-1] @ Wp[j*7+(i-1)], rows c*16..c*16+15 ----
        const int ci = b >> 2, c = b & 3;
        int i = 1;
        while (i < 7 && i * (i + 1) / 2 <= ci) ++i;
        const int j = ci - (i - 1) * i / 2;
        const int r = tid >> 4, q4 = tid & 15;        // row r (of 16), cols q4*4..+3
        const float* wh = Wh + (size_t)(i - 1) * 4096 + (c * 16 + r) * 64;
        const float* wp = Wp + (size_t)(j * 7 + (i - 1)) * 4096;
        float a4[4] = {0.f, 0.f, 0.f, 0.f};
#pragma unroll 4
        for (int t = 0; t < 64; ++t) {
            const float a = wh[t];
            const f32x4 r0 = *(const f32x4*)(wp + t * 64 + q4 * 4);
#pragma unroll
            for (int u = 0; u < 4; ++u) a4[u] += a * r0[u];
        }
#pragma unroll
        for (int u = 0; u < 4; ++u) M[r][q4 * 4 + u] = a4[u];
        __syncthreads();
        if (wv < 2) {   // chunk qq = 2c + wv (rows c*16.., k-half wv)
            const int kb = wv * 32 + (lane >> 4) * 8;
            half8 o;
#pragma unroll
            for (int e = 0; e < 8; ++e) o[e] = (_Float16)M[lane & 15][kb + e];
            *(half8*)(wsb + MAT_OFF + (size_t)ci * 8192 + (2 * c + wv) * 1024 + lane * 16) = o;
        }
    } else if (b < 139) {
        // ---- F[i,k] = sum_{jj=i+1..7} Wf[k*7+(jj-1)]  (+I if k==i) ----
        const int rr = b - 112;
        int i = 1;
        while (i < 6 && fOff(i + 1) <= rr) ++i;
        const int k = rr - fOff(i);
        const int m = tid >> 2, q = tid & 3;
        float acc[16];
#pragma unroll
        for (int u = 0; u < 16; ++u) acc[u] = 0.f;
        for (int jj = i + 1; jj <= 7; ++jj) {
            const f32x4* wf = (const f32x4*)(Wf + (size_t)(k * 7 + (jj - 1)) * 4096 + m * 64 + q * 16);
            const f32x4 r0 = wf[0], r1 = wf[1], r2 = wf[2], r3 = wf[3];
#pragma unroll
            for (int u = 0; u < 4; ++u) {
                acc[u]      += r0[u];
                acc[4 + u]  += r1[u];
                acc[8 + u]  += r2[u];
                acc[12 + u] += r3[u];
            }
        }
        if (k == i) {
#pragma unroll
            for (int u = 0; u < 16; ++u) acc[u] += (m == q * 16 + u) ? 1.0f : 0.0f;
        }
#pragma unroll
        for (int u = 0; u < 16; ++u) M[m][q * 16 + u] = acc[u];
        __syncthreads();
        const int slot = 28 + rr;
#pragma unroll
        for (int rep = 0; rep < 2; ++rep) {
            const int qq = wv + rep * 4;
            const int cc = qq >> 1, h = qq & 1;
            const int kb = h * 32 + (lane >> 4) * 8;
            half8 o;
#pragma unroll
            for (int e = 0; e < 8; ++e) o[e] = (_Float16)M[cc * 16 + (lane & 15)][kb + e];
            *(half8*)(wsb + MAT_OFF + (size_t)slot * 8192 + qq * 1024 + lane * 16) = o;
        }
    } else if (b < 164) {
        // ---- W0 zero-padded to K=800, frag order ----
        const int bb = b - 139;
        const int c = wv;
        const int rowW = c * 16 + (lane & 15);
        const int kb = bb * 32 + (lane >> 4) * 8;
        half8 o;
#pragma unroll
        for (int e = 0; e < 8; ++e) {
            const int k = kb + e;
            o[e] = (k < 784) ? (_Float16)W0[(size_t)rowW * 784 + k] : (_Float16)0.f;
        }
        *(half8*)(wsb + W0F_OFF + (size_t)(bb * 4 + c) * 1024 + lane * 16) = o;
    } else {
        // ---- Wout (10x64 zero-padded to 16x64), frag order ----
        if (tid < 128) {
            const int h = tid >> 6;
            const int mcol = lane & 15;
            const int kb = h * 32 + (lane >> 4) * 8;
            half8 o;
#pragma unroll
            for (int e = 0; e < 8; ++e)
                o[e] = (mcol < 10) ? (_Float16)Wout[mcol * 64 + kb + e] : (_Float16)0.f;
            *(half8*)(wsb + WOUT_OFF + (size_t)(h * 64 + lane) * 16) = o;
        }
    }
}

// ---------------- mlp_fused: layer0 + layers 1..7 + head + log_softmax ----------------
// 32 rows/wave, 512 blocks x 256 thr, 2 waves/SIMD.
__global__ __launch_bounds__(256, 2) void mlp_fused(const float* __restrict__ x,
                                                    const float* __restrict__ b0,
                                                    const float* __restrict__ bh,
                                                    const float* __restrict__ bout,
                                                    const char* __restrict__ wsb,
                                                    float* __restrict__ dOut) {
    __shared__ __align__(16) _Float16 scrh[4][2][1024];   // 2 x 2KB per wave
    const int tid = threadIdx.x, lane = tid & 63, wv = tid >> 6;
    const int rt2 = blockIdx.x * 4 + wv;               // 32-row group, 0..2047
    const int rowBase = rt2 * 32;
    const int m = lane & 15, g = lane >> 4;
    _Float16* sw0 = &scrh[wv][0][0];
    _Float16* sw1 = &scrh[wv][1][0];
    const half8* wm = (const half8*)(wsb + MAT_OFF);

    half8 stA[8][2][2];   // [layer][row-tile][k-half] (128 VGPRs)
    half8 pf0[8], pf1[8];
    loadTerm(pf0, wm, cIdx(1, 0), lane);   // term 0 prefetch (ready long before use)

    // ---- layer 0: out0 = silu(x @ W0^T + b0), both row-tiles interleaved ----
    {
        const float* xr0 = x + (size_t)(rowBase + m) * 784;
        const float* xr1 = x + (size_t)(rowBase + 16 + m) * 784;
        const int ko = g * 8;
        const half8* w0f = (const half8*)(wsb + W0F_OFF);
        f32x4 acc[2][4];
#pragma unroll
        for (int t = 0; t < 2; ++t)
#pragma unroll
            for (int c = 0; c < 4; ++c) acc[t][c] = (f32x4){0.f, 0.f, 0.f, 0.f};
#pragma unroll
        for (int t = 0; t < 24; ++t) {
            const f32x4 u0 = *(const f32x4*)(xr0 + t * 32 + ko);
            const f32x4 u1 = *(const f32x4*)(xr0 + t * 32 + ko + 4);
            const f32x4 v0 = *(const f32x4*)(xr1 + t * 32 + ko);
            const f32x4 v1 = *(const f32x4*)(xr1 + t * 32 + ko + 4);
            half8 a0, a1;
#pragma unroll
            for (int e = 0; e < 4; ++e) {
                a0[e] = (_Float16)u0[e]; a0[4 + e] = (_Float16)u1[e];
                a1[e] = (_Float16)v0[e]; a1[4 + e] = (_Float16)v1[e];
            }
#pragma unroll
            for (int c = 0; c < 4; ++c) {
                const half8 bf = w0f[(t * 4 + c) * 64 + lane];
                acc[0][c] = __builtin_amdgcn_mfma_f32_16x16x32_f16(a0, bf, acc[0][c], 0, 0, 0);
                acc[1][c] = __builtin_amdgcn_mfma_f32_16x16x32_f16(a1, bf, acc[1][c], 0, 0, 0);
            }
        }
        {   // t = 24 peel: k = 768 + ko, valid only for ko < 16 (row len 784)
            half8 a0, a1;
#pragma unroll
            for (int e = 0; e < 8; ++e) { a0[e] = (_Float16)0.f; a1[e] = (_Float16)0.f; }
            if (ko < 16) {
                const f32x4 u0 = *(const f32x4*)(xr0 + 768 + ko);
                const f32x4 u1 = *(const f32x4*)(xr0 + 768 + ko + 4);
                const f32x4 v0 = *(const f32x4*)(xr1 + 768 + ko);
                const f32x4 v1 = *(const f32x4*)(xr1 + 768 + ko + 4);
#pragma unroll
                for (int e = 0; e < 4; ++e) {
                    a0[e] = (_Float16)u0[e]; a0[4 + e] = (_Float16)u1[e];
                    a1[e] = (_Float16)v0[e]; a1[4 + e] = (_Float16)v1[e];
                }
            }
#pragma unroll
            for (int c = 0; c < 4; ++c) {
                const half8 bf = w0f[(24 * 4 + c) * 64 + lane];
                acc[0][c] = __builtin_amdgcn_mfma_f32_16x16x32_f16(a0, bf, acc[0][c], 0, 0, 0);
                acc[1][c] = __builtin_amdgcn_mfma_f32_16x16x32_f16(a1, bf, acc[1][c], 0, 0, 0);
            }
        }
#pragma unroll
        for (int t = 0; t < 2; ++t)
#pragma unroll
            for (int c = 0; c < 4; ++c) {
                const float bb = b0[c * 16 + m];
#pragma unroll
                for (int jj = 0; jj < 4; ++jj)
                    acc[t][c][jj] = fast_silu(acc[t][c][jj] + bb);
            }
        dToA(sw0, lane, acc[0], stA[0][0]);
        dToA(sw1, lane, acc[1], stA[0][1]);
    }

    f32x4 accL[2];
    accL[0] = (f32x4){0.f, 0.f, 0.f, 0.f};
    accL[1] = (f32x4){0.f, 0.f, 0.f, 0.f};
    half8 wo0, wo1;

    // term parity: per layer i the sequence is [C x i][self][F x i]; global
    // term counter at layer start nb = i*i-1; term T consumes pf[T&1].
#pragma unroll
    for (int i = 1; i < 8; ++i) {
        const int nb = i * i - 1;
        f32x4 acc[2][4];
#pragma unroll
        for (int c = 0; c < 4; ++c) {
            const float bb = bh[(i - 1) * 64 + c * 16 + m];
            acc[0][c] = (f32x4){bb, bb, bb, bb};
            acc[1][c] = (f32x4){bb, bb, bb, bb};
        }
        // ---- C-phase: sum_j out_j @ C[j,i]^T ----
#pragma unroll
        for (int tc = 0; tc < i; ++tc) {
            const bool hn = (tc + 1 < i) || (i < 7);
            const int ns = (tc + 1 < i) ? cIdx(i, tc + 1) : (i < 7 ? fIdx(i, i) : 0);
            if (((nb + tc) & 1) == 0) {
                if (hn) loadTerm(pf1, wm, ns, lane);
                term16(pf0, stA[tc][0], stA[tc][1], acc[0], acc[1]);
            } else {
                if (hn) loadTerm(pf0, wm, ns, lane);
                term16(pf1, stA[tc][0], stA[tc][1], acc[0], acc[1]);
            }
        }
        // silu + D->A (next term's loads already in flight)
#pragma unroll
        for (int t = 0; t < 2; ++t)
#pragma unroll
            for (int c = 0; c < 4; ++c)
#pragma unroll
                for (int jj = 0; jj < 4; ++jj)
                    acc[t][c][jj] = fast_silu(acc[t][c][jj]);
        if (i == 7) { // prefetch head weights so they overlap dToA
            const half8* wo = (const half8*)(wsb + WOUT_OFF);
            wo0 = wo[lane]; wo1 = wo[64 + lane];
        }
        half8 sA[2][2];
        dToA(sw0, lane, acc[0], sA[0]);
        dToA(sw1, lane, acc[1], sA[1]);

        if (i < 7) {
            f32x4 accO[2][4];
#pragma unroll
            for (int t = 0; t < 2; ++t)
#pragma unroll
                for (int c = 0; c < 4; ++c) accO[t][c] = (f32x4){0.f, 0.f, 0.f, 0.f};
            {   // self term FIRST (I + F[i,i]) -> sA dies here; prefetch F[i,0]
                const int ns = fIdx(i, 0);
                if (((nb + i) & 1) == 0) {
                    loadTerm(pf1, wm, ns, lane);
                    term16(pf0, sA[0], sA[1], accO[0], accO[1]);
                } else {
                    loadTerm(pf0, wm, ns, lane);
                    term16(pf1, sA[0], sA[1], accO[0], accO[1]);
                }
            }
            // ---- F-phase: sum_{k<i} out_k @ F[i,k]^T ----
#pragma unroll
            for (int k = 0; k < i; ++k) {
                const int ns = (k + 1 < i) ? fIdx(i, k + 1) : cIdx(i + 1, 0);
                if (((nb + i + 1 + k) & 1) == 0) {
                    loadTerm(pf1, wm, ns, lane);
                    term16(pf0, stA[k][0], stA[k][1], accO[0], accO[1]);
                } else {
                    loadTerm(pf0, wm, ns, lane);
                    term16(pf1, stA[k][0], stA[k][1], accO[0], accO[1]);
                }
            }
            dToA(sw0, lane, accO[0], &stA[i][0][0]);
            dToA(sw1, lane, accO[1], &stA[i][1][0]);
        } else {
            // logits = s7 @ Wout^T (single 16-col tile, K=64), per row-tile
#pragma unroll
            for (int t = 0; t < 2; ++t) {
                accL[t] = __builtin_amdgcn_mfma_f32_16x16x32_f16(sA[t][0], wo0, accL[t], 0, 0, 0);
                accL[t] = __builtin_amdgcn_mfma_f32_16x16x32_f16(sA[t][1], wo1, accL[t], 0, 0, 0);
            }
        }
    }

    // + bout, log_softmax over cols 0..9, store (per row-tile)
    const float bb = (m < 10) ? bout[m] : 0.f;
#pragma unroll
    for (int t = 0; t < 2; ++t)
#pragma unroll
        for (int jj = 0; jj < 4; ++jj) {
            const float logit = accL[t][jj] + bb;
            float mx = (m < 10) ? logit : -1e30f;
#pragma unroll
            for (int d = 1; d < 16; d <<= 1) mx = fmaxf(mx, __shfl_xor(mx, d, 16));
            const float e = (m < 10) ? __expf(logit - mx) : 0.f;
            float sum = e;
#pragma unroll
            for (int d = 1; d < 16; d <<= 1) sum += __shfl_xor(sum, d, 16);
            const float ls = logit - mx - __logf(sum);
            if (m < 10) dOut[(size_t)(rowBase + t * 16 + 4 * g + jj) * 10 + m] = ls;
        }
}

extern "C" void kernel_launch(void* const* d_in, const int* in_sizes, int n_in,
                              void* d_out, int out_size, void* d_ws, size_t ws_size,
                              hipStream_t stream) {
    (void)in_sizes; (void)n_in; (void)out_size; (void)ws_size;
    const float* x    = (const float*)d_in[0];
    const float* W0   = (const float*)d_in[1];
    const float* b0   = (const float*)d_in[2];
    const float* Wh   = (const float*)d_in[3];
    const float* bh   = (const float*)d_in[4];
    const float* Wp   = (const float*)d_in[5];
    const float* Wf   = (const float*)d_in[6];
    const float* Wout = (const float*)d_in[7];
    const float* bout = (const float*)d_in[8];
    char* wsb = (char*)d_ws;
    float* out = (float*)d_out;

    hipLaunchKernelGGL(prep_all,  dim3(165), dim3(256), 0, stream, W0, Wout, Wh, Wp, Wf, wsb);
    hipLaunchKernelGGL(mlp_fused, dim3(512), dim3(256), 0, stream, x, b0, bh, bout, wsb, out);
}